// Round 10
// baseline (320.498 us; speedup 1.0000x reference)
//
#include <hip/hip_runtime.h>

#define BB 2048
#define TT 512
#define KK 32

// 4-source viterbi block: strict > keeps first occurrence (np.argmax semantics)
// Named scalars ONLY — local arrays with non-constant indices get demoted to
// scratch (prior-session regression: 8x slowdown).
#define VBLK(q, t0, t1, t2, t3, base, m, bi) do {                       \
    float s0_ = (q).x + (t0), s1_ = (q).y + (t1);                       \
    float s2_ = (q).z + (t2), s3_ = (q).w + (t3);                       \
    m = s0_; bi = (base);                                               \
    if (s1_ > m) { m = s1_; bi = (base) + 1; }                          \
    if (s2_ > m) { m = s2_; bi = (base) + 2; }                          \
    if (s3_ > m) { m = s3_; bi = (base) + 3; }                          \
} while (0)

// ---------- FUSED forward step (viterbi + LSE in one wave) ----------
// R9 lesson: SIMD role-balancing via blockIdx-keyed rotation regressed
// (dispatch-mapping model wrong). Fusing makes every wave identical
// (~105 ops/step) -> per-SIMD balance by construction, and the two
// recurrence chains (alpha, beta) give in-wave ILP. One pot prefetch
// stream feeds both.
// alpha_T[j] = pot_T[j] + max_i(alpha_{T-1}[i] + trans[i][j])
// beta_T[j]  = pot_T[j] + log sum_i exp(beta_{T-1}[i] + trans[i][j])
#define FSTEP(T, PR) do {                                               \
    float nl_ = pot[min((T) + 8, last) * KK + j];                       \
    s_a[j] = alpha;                                                     \
    float M = __builtin_amdgcn_readfirstlane(beta);                     \
    float p_ = __expf(beta - M);                                        \
    s_p[j] = p_;                                                        \
    __builtin_amdgcn_wave_barrier();                                    \
    const float4 q0 = *(const float4*)(s_a + i0);                       \
    const float4 q1 = *(const float4*)(s_a + i0 + 4);                   \
    const float4 q2 = *(const float4*)(s_a + i0 + 8);                   \
    const float4 q3 = *(const float4*)(s_a + i0 + 12);                  \
    const float4 r0 = *(const float4*)(s_p + i0);                       \
    const float4 r1 = *(const float4*)(s_p + i0 + 4);                   \
    const float4 r2 = *(const float4*)(s_p + i0 + 8);                   \
    const float4 r3 = *(const float4*)(s_p + i0 + 12);                  \
    float m0, m1, m2, m3; int b0, b1, b2, b3;                           \
    VBLK(q0, tA[0],  tA[1],  tA[2],  tA[3],  i0 + 0,  m0, b0);          \
    VBLK(q1, tA[4],  tA[5],  tA[6],  tA[7],  i0 + 4,  m1, b1);          \
    VBLK(q2, tA[8],  tA[9],  tA[10], tA[11], i0 + 8,  m2, b2);          \
    VBLK(q3, tA[12], tA[13], tA[14], tA[15], i0 + 12, m3, b3);          \
    if (m1 > m0) { m0 = m1; b0 = b1; }                                  \
    if (m3 > m2) { m2 = m3; b2 = b3; }                                  \
    if (m2 > m0) { m0 = m2; b0 = b2; }                                  \
    float om = __shfl_xor(m0, 32, 64);                                  \
    int   ob = __shfl_xor(b0, 32, 64);                                  \
    bool won = half ? (m0 > om) : (m0 >= om);                           \
    float mm = fmaxf(m0, om);                                           \
    int bwin_ = won ? b0 : ob;                                          \
    if (won) s_bp[(T) * KK + j] = (unsigned char)b0;                    \
    cmap = __shfl(cmap, bwin_, 64);                                     \
    if (((T) & 31) == 0) {                                              \
        s_cmF[((((T) >> 5) - 1) << 5) + j] = (unsigned char)cmap;       \
        cmap = j;                                                       \
    }                                                                   \
    float a0 = fmaf(r0.x, tE[0],  r0.y * tE[1]);                        \
    a0 = fmaf(r0.z, tE[2],  a0); a0 = fmaf(r0.w, tE[3],  a0);           \
    float a1 = fmaf(r1.x, tE[4],  r1.y * tE[5]);                        \
    a1 = fmaf(r1.z, tE[6],  a1); a1 = fmaf(r1.w, tE[7],  a1);           \
    float a2 = fmaf(r2.x, tE[8],  r2.y * tE[9]);                        \
    a2 = fmaf(r2.z, tE[10], a2); a2 = fmaf(r2.w, tE[11], a2);           \
    float a3 = fmaf(r3.x, tE[12], r3.y * tE[13]);                       \
    a3 = fmaf(r3.z, tE[14], a3); a3 = fmaf(r3.w, tE[15], a3);           \
    float ssum = (a0 + a1) + (a2 + a3);                                 \
    ssum += __shfl_xor(ssum, 32, 64);                                   \
    alpha = PR + mm;                                                    \
    beta  = PR + M + __logf(ssum);                                      \
    PR = nl_;                                                           \
} while (0)

// ---------- FUSED backward step ----------
// gamma_T[j] = pot_T[j] + max_k(trans[j][k] + gamma_{T+1}[k])
// gl_T[j]    = pot_T[j] + log sum_k exp(trans[j][k] + gl_{T+1}[k])
// bp_bwd (tag@T -> tag@T+1) stored at s_bp row T+1 (disjoint from fwd rows).
#define BSTEP(T, PR) do {                                               \
    float nl_ = pot[max((T) - 8, 0) * KK + j];                          \
    s_g[j] = gamma;                                                     \
    float M = __builtin_amdgcn_readfirstlane(gl);                       \
    float p_ = __expf(gl - M);                                          \
    s_q[j] = p_;                                                        \
    __builtin_amdgcn_wave_barrier();                                    \
    const float4 q0 = *(const float4*)(s_g + i0);                       \
    const float4 q1 = *(const float4*)(s_g + i0 + 4);                   \
    const float4 q2 = *(const float4*)(s_g + i0 + 8);                   \
    const float4 q3 = *(const float4*)(s_g + i0 + 12);                  \
    const float4 r0 = *(const float4*)(s_q + i0);                       \
    const float4 r1 = *(const float4*)(s_q + i0 + 4);                   \
    const float4 r2 = *(const float4*)(s_q + i0 + 8);                   \
    const float4 r3 = *(const float4*)(s_q + i0 + 12);                  \
    float m0, m1, m2, m3; int b0, b1, b2, b3;                           \
    VBLK(q0, tB[0],  tB[1],  tB[2],  tB[3],  i0 + 0,  m0, b0);          \
    VBLK(q1, tB[4],  tB[5],  tB[6],  tB[7],  i0 + 4,  m1, b1);          \
    VBLK(q2, tB[8],  tB[9],  tB[10], tB[11], i0 + 8,  m2, b2);          \
    VBLK(q3, tB[12], tB[13], tB[14], tB[15], i0 + 12, m3, b3);          \
    if (m1 > m0) { m0 = m1; b0 = b1; }                                  \
    if (m3 > m2) { m2 = m3; b2 = b3; }                                  \
    if (m2 > m0) { m0 = m2; b0 = b2; }                                  \
    float om = __shfl_xor(m0, 32, 64);                                  \
    int   ob = __shfl_xor(b0, 32, 64);                                  \
    bool won = half ? (m0 > om) : (m0 >= om);                           \
    float mm = fmaxf(m0, om);                                           \
    int bwin_ = won ? b0 : ob;                                          \
    if (won) s_bp[((T) + 1) * KK + j] = (unsigned char)b0;              \
    cmapb = __shfl(cmapb, bwin_, 64);                                   \
    if ((((T) - m) & 31) == 0) {                                        \
        s_cmB[((((T) - m) >> 5) << 5) + j] = (unsigned char)cmapb;      \
        cmapb = j;                                                      \
    }                                                                   \
    float a0 = fmaf(r0.x, tEB[0],  r0.y * tEB[1]);                      \
    a0 = fmaf(r0.z, tEB[2],  a0); a0 = fmaf(r0.w, tEB[3],  a0);         \
    float a1 = fmaf(r1.x, tEB[4],  r1.y * tEB[5]);                      \
    a1 = fmaf(r1.z, tEB[6],  a1); a1 = fmaf(r1.w, tEB[7],  a1);         \
    float a2 = fmaf(r2.x, tEB[8],  r2.y * tEB[9]);                      \
    a2 = fmaf(r2.z, tEB[10], a2); a2 = fmaf(r2.w, tEB[11], a2);         \
    float a3 = fmaf(r3.x, tEB[12], r3.y * tEB[13]);                     \
    a3 = fmaf(r3.z, tEB[14], a3); a3 = fmaf(r3.w, tEB[15], a3);         \
    float ssum = (a0 + a1) + (a2 + a3);                                 \
    ssum += __shfl_xor(ssum, 32, 64);                                   \
    gamma = PR + mm;                                                    \
    gl    = PR + M + __logf(ssum);                                      \
    PR = nl_;                                                           \
} while (0)

// ---------- LPT scheduler: perm = block ids sorted by DESCENDING seqlen ----------
// Counting sort, 1 block / 512 threads. Verified R8 win (+48us): long blocks
// start first, shorts backfill -> makespan tail shrinks.
__launch_bounds__(512)
__global__ void build_perm(const int* __restrict__ seqlen,
                           int* __restrict__ perm) {
    __shared__ int hist[TT + 1];
    const int tid = threadIdx.x;
    for (int i = tid; i <= TT; i += 512) hist[i] = 0;
    __syncthreads();
    for (int i = tid; i < BB; i += 512) atomicAdd(&hist[seqlen[i]], 1);
    __syncthreads();
    if (tid == 0) {
        int acc = 0;
        for (int L = TT; L >= 1; --L) { int c = hist[L]; hist[L] = acc; acc += c; }
    }
    __syncthreads();
    for (int i = tid; i < BB; i += 512) {
        int pos = atomicAdd(&hist[seqlen[i]], 1);
        perm[pos] = i;
    }
}

__launch_bounds__(128)
__global__ void crf_kernel(const float* __restrict__ pot_g,
                           const float* __restrict__ trans,
                           const int* __restrict__ seqlen,
                           const int* __restrict__ tagidx,
                           float* __restrict__ out,
                           const int* __restrict__ perm,
                           int use_perm) {
    __shared__ __align__(16) float s_a[KK];          // fwd alpha broadcast (wv0)
    __shared__ __align__(16) float s_g[KK];          // bwd gamma broadcast (wv1)
    __shared__ __align__(16) float s_p[KK];          // fwd LSE broadcast (wv0)
    __shared__ __align__(16) float s_q[KK];          // bwd LSE broadcast (wv1)
    __shared__ unsigned char s_bp[TT * KK];          // fwd rows 1..m, bwd rows m+1..last
    __shared__ unsigned char s_cmF[8 * KK];          // fwd chunk maps (<=8 full chunks)
    __shared__ unsigned char s_cmB[10 * KK];         // bwd chunk maps (<=9 chunks)

    const int tid  = threadIdx.x;
    const int wv   = tid >> 6;
    const int lane = tid & 63;
    const int j    = lane & 31;
    const int half = lane >> 5;
    const int i0   = half << 4;
    const int b    = use_perm ? perm[blockIdx.x] : blockIdx.x;

    const float* pot = pot_g + (size_t)b * (TT * KK);
    const int len  = seqlen[b];
    const int last = len - 1;
    // meeting point: multiple of 32 so all fwd chunks are full
    const int m = ((last + 1) >> 1) & ~31;
    float* out_tags = out + (size_t)b * TT;
    float su = 0.0f;                                 // seq score (wv0)

    if (wv == 0) {
        // ============ fwd fused: alpha/beta_0 .. alpha/beta_m + seq score ============
        float tA[16], tE[16];
#pragma unroll
        for (int k = 0; k < 16; ++k) {
            tA[k] = trans[(i0 + k) * KK + j];
            tE[k] = __expf(tA[k]);
        }
        const int* tagrow = tagidx + (size_t)b * TT;
#pragma unroll
        for (int c = 0; c < TT / 64; ++c) {
            int tt = c * 64 + lane;
            if (tt < len) {
                int tg = tagrow[tt];
                su += pot[tt * KK + tg];
                if (tt < last) {
                    int tg2 = tagrow[tt + 1];
                    su += trans[tg * KK + tg2];
                }
            }
        }
#pragma unroll
        for (int d = 1; d < 64; d <<= 1) su += __shfl_xor(su, d, 64);

        int cmap = j;
        float alpha = pot[j];
        float beta  = alpha;
        float pr0 = pot[min(1, last) * KK + j];
        float pr1 = pot[min(2, last) * KK + j];
        float pr2 = pot[min(3, last) * KK + j];
        float pr3 = pot[min(4, last) * KK + j];
        float pr4 = pot[min(5, last) * KK + j];
        float pr5 = pot[min(6, last) * KK + j];
        float pr6 = pot[min(7, last) * KK + j];
        float pr7 = pot[min(8, last) * KK + j];
        int t = 1;
        for (; t + 7 <= m; t += 8) {
            FSTEP(t,     pr0); FSTEP(t + 1, pr1);
            FSTEP(t + 2, pr2); FSTEP(t + 3, pr3);
            FSTEP(t + 4, pr4); FSTEP(t + 5, pr5);
            FSTEP(t + 6, pr6); FSTEP(t + 7, pr7);
        }
        // m % 32 == 0 with unroll 8: loop lands exactly on t = m+1.
        s_a[j] = alpha;                 // alpha_m
        s_p[j] = beta;                  // beta_m  (overwrites p broadcast)
    } else {
        // ============ bwd fused: gamma/gl_last .. gamma/gl_m ============
        float tB[16], tEB[16];
#pragma unroll
        for (int k = 0; k < 16; ++k) {
            tB[k]  = trans[j * KK + i0 + k];
            tEB[k] = __expf(tB[k]);
        }
        int cmapb = j;
        float gamma = pot[last * KK + j];
        float gl    = gamma;
        float pr0 = pot[max(last - 1, 0) * KK + j];
        float pr1 = pot[max(last - 2, 0) * KK + j];
        float pr2 = pot[max(last - 3, 0) * KK + j];
        float pr3 = pot[max(last - 4, 0) * KK + j];
        float pr4 = pot[max(last - 5, 0) * KK + j];
        float pr5 = pot[max(last - 6, 0) * KK + j];
        float pr6 = pot[max(last - 7, 0) * KK + j];
        float pr7 = pot[max(last - 8, 0) * KK + j];
        int t = last - 1;
        for (; t - 7 >= m; t -= 8) {
            BSTEP(t,     pr0); BSTEP(t - 1, pr1);
            BSTEP(t - 2, pr2); BSTEP(t - 3, pr3);
            BSTEP(t - 4, pr4); BSTEP(t - 5, pr5);
            BSTEP(t - 6, pr6); BSTEP(t - 7, pr7);
        }
        if (t >= m) { BSTEP(t, pr0); --t; }
        if (t >= m) { BSTEP(t, pr1); --t; }
        if (t >= m) { BSTEP(t, pr2); --t; }
        if (t >= m) { BSTEP(t, pr3); --t; }
        if (t >= m) { BSTEP(t, pr4); --t; }
        if (t >= m) { BSTEP(t, pr5); --t; }
        if (t >= m) { BSTEP(t, pr6); --t; }
        s_g[j] = gamma;                 // gamma_m
        s_q[j] = gl;                    // gl_m
    }

    __syncthreads();

    // joint best at the meeting point (both waves compute it; avoids a 2nd sync)
    {
        float v = s_a[j] + s_g[j] - pot[m * KK + j];
        float bv = v; int bj = j;
#pragma unroll
        for (int d = 1; d < 32; d <<= 1) {
            float ov = __shfl_xor(bv, d, 64);
            int   oj = __shfl_xor(bj, d, 64);
            if (ov > bv || (ov == bv && oj < bj)) { bv = ov; bj = oj; }
        }
        if (wv == 0) {
            if (lane == 0) {
                out[(size_t)BB * TT + b] = bv;       // best_score
                out_tags[m] = (float)bj;             // meeting tag
            }
            // fwd backtrace: t in [0, m-1]; all chunks full (m % 32 == 0)
            const int C_f = m >> 5;
            int e = bj, my_e = bj;
            for (int c = C_f - 1; c >= 1; --c) {
                e = s_cmF[(c << 5) + e];             // tag @ 32*c (uniform)
                if (lane == c - 1) my_e = e;
            }
            if (lane < C_f) {
                int cur = my_e;                      // tag @ 32*(lane+1)
                const int tend = (lane << 5) + 32;
#pragma unroll
                for (int r = 0; r < 32; ++r) {
                    int tt = tend - r;
                    cur = s_bp[tt * KK + cur];       // tag @ tt-1
                    out_tags[tt - 1] = (float)cur;
                }
            }
            // logZ = LSE_i(beta_m[i] + gl_m[i] - pot_m[i]); ll = su - logZ
            float v2 = s_p[j] + s_q[j] - pot[m * KK + j];
            float Mf = v2;
#pragma unroll
            for (int d = 1; d < 32; d <<= 1) Mf = fmaxf(Mf, __shfl_xor(Mf, d, 64));
            float e2 = __expf(v2 - Mf);
#pragma unroll
            for (int d = 1; d < 32; d <<= 1) e2 += __shfl_xor(e2, d, 64);
            float ln = Mf + __logf(e2);
            if (lane == 0) out[(size_t)BB * TT + BB + b] = su - ln;
        } else {
            // bwd backtrace: t in [m+1, last]; bp_bwd[t] stored at row t+1
            const int C_b = (last - m + 31) >> 5;
            int e = bj, my_e = bj;
            for (int c = 0; c < C_b; ++c) {
                if (lane == c) my_e = e;             // tag @ m+32c
                e = s_cmB[(c << 5) + e];
            }
            // e = tag @ last now
            if (lane < C_b) {
                int cur = my_e;
                const int tlo = m + (lane << 5);
                const int thi = min(tlo + 31, last - 1);
#pragma unroll
                for (int r = 0; r < 32; ++r) {
                    int tt = tlo + r;
                    if (tt <= thi) {
                        cur = s_bp[(tt + 1) * KK + cur];   // tag @ tt+1
                        out_tags[tt + 1] = (float)cur;
                    }
                }
            }
            for (int tt = last + 1 + lane; tt < TT; tt += 64)
                out_tags[tt] = (float)e;             // padding = final tag
        }
    }
}

extern "C" void kernel_launch(void* const* d_in, const int* in_sizes, int n_in,
                              void* d_out, int out_size, void* d_ws, size_t ws_size,
                              hipStream_t stream) {
    const float* potentials = (const float*)d_in[0];
    const float* transitions = (const float*)d_in[1];
    const int* sequence_lengths = (const int*)d_in[2];
    const int* tag_indices = (const int*)d_in[3];
    float* out = (float*)d_out;
    int* perm = (int*)d_ws;
    const int use_perm = (ws_size >= BB * sizeof(int)) ? 1 : 0;
    if (use_perm)
        build_perm<<<1, 512, 0, stream>>>(sequence_lengths, perm);
    crf_kernel<<<BB, 128, 0, stream>>>(potentials, transitions, sequence_lengths,
                                       tag_indices, out, perm, use_perm);
}

// Round 11
// 308.887 us; speedup vs baseline: 1.0376x; 1.0376x over previous
//
#include <hip/hip_runtime.h>

#define BB 2048
#define TT 512
#define KK 32

// 4-source viterbi block: strict > keeps first occurrence (np.argmax semantics)
// Named scalars ONLY — local arrays with non-constant indices get demoted to
// scratch (prior-session regression: 8x slowdown).
#define VBLK(q, t0, t1, t2, t3, base, m, bi) do {                       \
    float s0_ = (q).x + (t0), s1_ = (q).y + (t1);                       \
    float s2_ = (q).z + (t2), s3_ = (q).w + (t3);                       \
    m = s0_; bi = (base);                                               \
    if (s1_ > m) { m = s1_; bi = (base) + 1; }                          \
    if (s2_ > m) { m = s2_; bi = (base) + 2; }                          \
    if (s3_ > m) { m = s3_; bi = (base) + 3; }                          \
} while (0)

// ---------- forward viterbi step (t ascending, 1..m) ----------
// alpha_T[j] = pot_T[j] + max_i(alpha_{T-1}[i] + trans[i][j])
// bp_fwd stored at s_bp row T (map tag@T -> tag@T-1).
// m is a multiple of 32 so all fwd chunks are full (stash at T%32==0).
// R6 lesson: LDS-broadcast beats readlane-broadcast. R10 lesson: keep
// separate role waves (fusion halves TLP -> latency-bound).
#define VSTEPF(T, PR) do {                                              \
    float nl_ = pot[min((T) + 8, last) * KK + j];                       \
    s_a[j] = alpha;                                                     \
    __builtin_amdgcn_wave_barrier();                                    \
    const float4 q0 = *(const float4*)(s_a + i0);                       \
    const float4 q1 = *(const float4*)(s_a + i0 + 4);                   \
    const float4 q2 = *(const float4*)(s_a + i0 + 8);                   \
    const float4 q3 = *(const float4*)(s_a + i0 + 12);                  \
    float m0, m1, m2, m3; int b0, b1, b2, b3;                           \
    VBLK(q0, tA[0],  tA[1],  tA[2],  tA[3],  i0 + 0,  m0, b0);          \
    VBLK(q1, tA[4],  tA[5],  tA[6],  tA[7],  i0 + 4,  m1, b1);          \
    VBLK(q2, tA[8],  tA[9],  tA[10], tA[11], i0 + 8,  m2, b2);          \
    VBLK(q3, tA[12], tA[13], tA[14], tA[15], i0 + 12, m3, b3);          \
    if (m1 > m0) { m0 = m1; b0 = b1; }                                  \
    if (m3 > m2) { m2 = m3; b2 = b3; }                                  \
    if (m2 > m0) { m0 = m2; b0 = b2; }                                  \
    float om = __shfl_xor(m0, 32, 64);                                  \
    int   ob = __shfl_xor(b0, 32, 64);                                  \
    bool won = half ? (m0 > om) : (m0 >= om);                           \
    float mm = fmaxf(m0, om);                                           \
    int bwin_ = won ? b0 : ob;                                          \
    if (won) s_bp[(T) * KK + j] = (unsigned char)b0;                    \
    cmap = __shfl(cmap, bwin_, 64);                                     \
    if (((T) & 31) == 0) {                                              \
        s_cmF[((((T) >> 5) - 1) << 5) + j] = (unsigned char)cmap;       \
        cmap = j;                                                       \
    }                                                                   \
    alpha = PR + mm;                                                    \
    PR = nl_;                                                           \
} while (0)

// ---------- backward viterbi step (t descending, last-1..m) ----------
// gamma_T[j] = pot_T[j] + max_k(trans[j][k] + gamma_{T+1}[k])
// bp_bwd (tag@T -> tag@T+1) stored at s_bp row T+1 (disjoint from fwd rows).
#define VSTEPB(T, PR) do {                                              \
    float nl_ = pot[max((T) - 8, 0) * KK + j];                          \
    s_g[j] = gamma;                                                     \
    __builtin_amdgcn_wave_barrier();                                    \
    const float4 q0 = *(const float4*)(s_g + i0);                       \
    const float4 q1 = *(const float4*)(s_g + i0 + 4);                   \
    const float4 q2 = *(const float4*)(s_g + i0 + 8);                   \
    const float4 q3 = *(const float4*)(s_g + i0 + 12);                  \
    float m0, m1, m2, m3; int b0, b1, b2, b3;                           \
    VBLK(q0, tB[0],  tB[1],  tB[2],  tB[3],  i0 + 0,  m0, b0);          \
    VBLK(q1, tB[4],  tB[5],  tB[6],  tB[7],  i0 + 4,  m1, b1);          \
    VBLK(q2, tB[8],  tB[9],  tB[10], tB[11], i0 + 8,  m2, b2);          \
    VBLK(q3, tB[12], tB[13], tB[14], tB[15], i0 + 12, m3, b3);          \
    if (m1 > m0) { m0 = m1; b0 = b1; }                                  \
    if (m3 > m2) { m2 = m3; b2 = b3; }                                  \
    if (m2 > m0) { m0 = m2; b0 = b2; }                                  \
    float om = __shfl_xor(m0, 32, 64);                                  \
    int   ob = __shfl_xor(b0, 32, 64);                                  \
    bool won = half ? (m0 > om) : (m0 >= om);                           \
    float mm = fmaxf(m0, om);                                           \
    int bwin_ = won ? b0 : ob;                                          \
    if (won) s_bp[((T) + 1) * KK + j] = (unsigned char)b0;              \
    cmapb = __shfl(cmapb, bwin_, 64);                                   \
    if ((((T) - m) & 31) == 0) {                                        \
        s_cmB[((((T) - m) >> 5) << 5) + j] = (unsigned char)cmapb;      \
        cmapb = j;                                                      \
    }                                                                   \
    gamma = PR + mm;                                                    \
    PR = nl_;                                                           \
} while (0)

// ---------- forward LSE step ----------
#define LSTEPF(T, PR) do {                                              \
    float nl_ = pot[min((T) + 8, last) * KK + j];                       \
    float M = __builtin_amdgcn_readfirstlane(beta);                     \
    float p = __expf(beta - M);                                         \
    s_p[j] = p;                                                         \
    __builtin_amdgcn_wave_barrier();                                    \
    const float4 q0 = *(const float4*)(s_p + i0);                       \
    const float4 q1 = *(const float4*)(s_p + i0 + 4);                   \
    const float4 q2 = *(const float4*)(s_p + i0 + 8);                   \
    const float4 q3 = *(const float4*)(s_p + i0 + 12);                  \
    float a0 = fmaf(q0.x, tE[0],  q0.y * tE[1]);                        \
    a0 = fmaf(q0.z, tE[2],  a0); a0 = fmaf(q0.w, tE[3],  a0);           \
    float a1 = fmaf(q1.x, tE[4],  q1.y * tE[5]);                        \
    a1 = fmaf(q1.z, tE[6],  a1); a1 = fmaf(q1.w, tE[7],  a1);           \
    float a2 = fmaf(q2.x, tE[8],  q2.y * tE[9]);                        \
    a2 = fmaf(q2.z, tE[10], a2); a2 = fmaf(q2.w, tE[11], a2);           \
    float a3 = fmaf(q3.x, tE[12], q3.y * tE[13]);                       \
    a3 = fmaf(q3.z, tE[14], a3); a3 = fmaf(q3.w, tE[15], a3);           \
    float ssum = (a0 + a1) + (a2 + a3);                                 \
    ssum += __shfl_xor(ssum, 32, 64);                                   \
    beta = PR + M + __logf(ssum);                                       \
    PR = nl_;                                                           \
} while (0)

// ---------- backward LSE step ----------
// gl_T[j] = pot_T[j] + log sum_k exp(trans[j][k]) * exp(gl_{T+1}[k])
#define LSTEPB(T, PR) do {                                              \
    float nl_ = pot[max((T) - 8, 0) * KK + j];                          \
    float M = __builtin_amdgcn_readfirstlane(gl);                       \
    float p = __expf(gl - M);                                           \
    s_q[j] = p;                                                         \
    __builtin_amdgcn_wave_barrier();                                    \
    const float4 q0 = *(const float4*)(s_q + i0);                       \
    const float4 q1 = *(const float4*)(s_q + i0 + 4);                   \
    const float4 q2 = *(const float4*)(s_q + i0 + 8);                   \
    const float4 q3 = *(const float4*)(s_q + i0 + 12);                  \
    float a0 = fmaf(q0.x, tEB[0],  q0.y * tEB[1]);                      \
    a0 = fmaf(q0.z, tEB[2],  a0); a0 = fmaf(q0.w, tEB[3],  a0);         \
    float a1 = fmaf(q1.x, tEB[4],  q1.y * tEB[5]);                      \
    a1 = fmaf(q1.z, tEB[6],  a1); a1 = fmaf(q1.w, tEB[7],  a1);         \
    float a2 = fmaf(q2.x, tEB[8],  q2.y * tEB[9]);                      \
    a2 = fmaf(q2.z, tEB[10], a2); a2 = fmaf(q2.w, tEB[11], a2);         \
    float a3 = fmaf(q3.x, tEB[12], q3.y * tEB[13]);                     \
    a3 = fmaf(q3.z, tEB[14], a3); a3 = fmaf(q3.w, tEB[15], a3);         \
    float ssum = (a0 + a1) + (a2 + a3);                                 \
    ssum += __shfl_xor(ssum, 32, 64);                                   \
    gl = PR + M + __logf(ssum);                                         \
    PR = nl_;                                                           \
} while (0)

// ---------- LPT scheduler: perm = block ids sorted by DESCENDING seqlen ----------
// Counting sort, 1 block / 512 threads. Verified R8 win (+48us). With 2 seqs
// per block, pairing consecutive perm entries gives near-equal pair lengths.
__launch_bounds__(512)
__global__ void build_perm(const int* __restrict__ seqlen,
                           int* __restrict__ perm) {
    __shared__ int hist[TT + 1];
    const int tid = threadIdx.x;
    for (int i = tid; i <= TT; i += 512) hist[i] = 0;
    __syncthreads();
    for (int i = tid; i < BB; i += 512) atomicAdd(&hist[seqlen[i]], 1);
    __syncthreads();
    if (tid == 0) {
        int acc = 0;
        for (int L = TT; L >= 1; --L) { int c = hist[L]; hist[L] = acc; acc += c; }
    }
    __syncthreads();
    for (int i = tid; i < BB; i += 512) {
        int pos = atomicAdd(&hist[seqlen[i]], 1);
        perm[pos] = i;
    }
}

// 2 sequences per 512-thread block; 8 equal-role waves.
// Role layout: wv0-3 = seqA roles {0,1,2,3}; wv4-7 = seqB roles {2,3,0,1}
// (XOR-rotation). Under a wv%4 wave->SIMD mapping each SIMD hosts one
// viterbi (140 ops/step) + one LSE (70) wave per block -> per-SIMD issue
// balanced by construction (R8's 76% VALUBusy == viterbi SIMDs saturated,
// LSE SIMDs half-idle). Grid 1024 = exactly 4 blocks/CU (LDS 34.9KB x4),
// 32 waves/CU full residency: no dispatch-order tail, 8 waves/SIMD TLP
// (R10 lesson: 4/SIMD is not enough).
__launch_bounds__(512)
__global__ void crf_kernel(const float* __restrict__ pot_g,
                           const float* __restrict__ trans,
                           const int* __restrict__ seqlen,
                           const int* __restrict__ tagidx,
                           float* __restrict__ out,
                           const int* __restrict__ perm,
                           int use_perm) {
    __shared__ __align__(16) float s_aS[2][KK];      // fwd alpha broadcast (role 0)
    __shared__ __align__(16) float s_gS[2][KK];      // bwd gamma broadcast (role 1)
    __shared__ __align__(16) float s_pS[2][KK];      // fwd LSE broadcast (role 2)
    __shared__ __align__(16) float s_qS[2][KK];      // bwd LSE broadcast (role 3)
    __shared__ unsigned char s_bpS[2][TT * KK];      // per-seq backpointers
    __shared__ unsigned char s_cmFS[2][8 * KK];      // fwd chunk maps
    __shared__ unsigned char s_cmBS[2][10 * KK];     // bwd chunk maps

    const int tid  = threadIdx.x;
    const int wv   = tid >> 6;                       // 0..7
    const int seq  = wv >> 2;                        // 0 / 1
    const int role = (wv & 3) ^ (seq << 1);          // seqB: 2,3,0,1
    const int lane = tid & 63;
    const int j    = lane & 31;
    const int half = lane >> 5;
    const int i0   = half << 4;
    const int bidx = 2 * blockIdx.x + seq;
    const int b    = use_perm ? perm[bidx] : bidx;

    float* s_a = s_aS[seq];
    float* s_g = s_gS[seq];
    float* s_p = s_pS[seq];
    float* s_q = s_qS[seq];
    unsigned char* s_bp  = s_bpS[seq];
    unsigned char* s_cmF = s_cmFS[seq];
    unsigned char* s_cmB = s_cmBS[seq];

    const float* pot = pot_g + (size_t)b * (TT * KK);
    const int len  = seqlen[b];
    const int last = len - 1;
    // meeting point: multiple of 32 so all fwd chunks are full
    const int m = ((last + 1) >> 1) & ~31;
    float* out_tags = out + (size_t)b * TT;

    if (role == 0) {
        // ============ forward viterbi: alpha_0 .. alpha_m ============
        float tA[16];
#pragma unroll
        for (int k = 0; k < 16; ++k) tA[k] = trans[(i0 + k) * KK + j];
        int cmap = j;
        float alpha = pot[j];
        float pr0 = pot[min(1, last) * KK + j];
        float pr1 = pot[min(2, last) * KK + j];
        float pr2 = pot[min(3, last) * KK + j];
        float pr3 = pot[min(4, last) * KK + j];
        float pr4 = pot[min(5, last) * KK + j];
        float pr5 = pot[min(6, last) * KK + j];
        float pr6 = pot[min(7, last) * KK + j];
        float pr7 = pot[min(8, last) * KK + j];
        int t = 1;
        for (; t + 7 <= m; t += 8) {
            VSTEPF(t,     pr0); VSTEPF(t + 1, pr1);
            VSTEPF(t + 2, pr2); VSTEPF(t + 3, pr3);
            VSTEPF(t + 4, pr4); VSTEPF(t + 5, pr5);
            VSTEPF(t + 6, pr6); VSTEPF(t + 7, pr7);
        }
        // m % 32 == 0 with unroll 8: loop lands exactly on t = m+1.
        s_a[j] = alpha;                 // alpha_m
    } else if (role == 1) {
        // ============ backward viterbi: gamma_last .. gamma_m ============
        float tB[16];
#pragma unroll
        for (int k = 0; k < 16; ++k) tB[k] = trans[j * KK + i0 + k];
        int cmapb = j;
        float gamma = pot[last * KK + j];
        float pr0 = pot[max(last - 1, 0) * KK + j];
        float pr1 = pot[max(last - 2, 0) * KK + j];
        float pr2 = pot[max(last - 3, 0) * KK + j];
        float pr3 = pot[max(last - 4, 0) * KK + j];
        float pr4 = pot[max(last - 5, 0) * KK + j];
        float pr5 = pot[max(last - 6, 0) * KK + j];
        float pr6 = pot[max(last - 7, 0) * KK + j];
        float pr7 = pot[max(last - 8, 0) * KK + j];
        int t = last - 1;
        for (; t - 7 >= m; t -= 8) {
            VSTEPB(t,     pr0); VSTEPB(t - 1, pr1);
            VSTEPB(t - 2, pr2); VSTEPB(t - 3, pr3);
            VSTEPB(t - 4, pr4); VSTEPB(t - 5, pr5);
            VSTEPB(t - 6, pr6); VSTEPB(t - 7, pr7);
        }
        if (t >= m) { VSTEPB(t, pr0); --t; }
        if (t >= m) { VSTEPB(t, pr1); --t; }
        if (t >= m) { VSTEPB(t, pr2); --t; }
        if (t >= m) { VSTEPB(t, pr3); --t; }
        if (t >= m) { VSTEPB(t, pr4); --t; }
        if (t >= m) { VSTEPB(t, pr5); --t; }
        if (t >= m) { VSTEPB(t, pr6); --t; }
        s_g[j] = gamma;                 // gamma_m
    } else if (role == 2) {
        // ============ seq-score + forward LSE: beta_0 .. beta_m ============
        float tE[16];
#pragma unroll
        for (int k = 0; k < 16; ++k) tE[k] = __expf(trans[(i0 + k) * KK + j]);
        const int* tagrow = tagidx + (size_t)b * TT;
        float su = 0.0f;
#pragma unroll
        for (int c = 0; c < TT / 64; ++c) {
            int tt = c * 64 + lane;
            if (tt < len) {
                int tg = tagrow[tt];
                su += pot[tt * KK + tg];
                if (tt < last) {
                    int tg2 = tagrow[tt + 1];
                    su += trans[tg * KK + tg2];
                }
            }
        }
#pragma unroll
        for (int d = 1; d < 64; d <<= 1) su += __shfl_xor(su, d, 64);
        if (lane == 0) out[(size_t)BB * TT + BB + b] = su;  // stash su; ln added post-sync

        float beta = pot[j];
        float pr0 = pot[min(1, last) * KK + j];
        float pr1 = pot[min(2, last) * KK + j];
        float pr2 = pot[min(3, last) * KK + j];
        float pr3 = pot[min(4, last) * KK + j];
        float pr4 = pot[min(5, last) * KK + j];
        float pr5 = pot[min(6, last) * KK + j];
        float pr6 = pot[min(7, last) * KK + j];
        float pr7 = pot[min(8, last) * KK + j];
        int t = 1;
        for (; t + 7 <= m; t += 8) {
            LSTEPF(t,     pr0); LSTEPF(t + 1, pr1);
            LSTEPF(t + 2, pr2); LSTEPF(t + 3, pr3);
            LSTEPF(t + 4, pr4); LSTEPF(t + 5, pr5);
            LSTEPF(t + 6, pr6); LSTEPF(t + 7, pr7);
        }
        s_p[j] = beta;                  // beta_m
    } else {
        // ============ backward LSE: gl_last .. gl_m ============
        float tEB[16];
#pragma unroll
        for (int k = 0; k < 16; ++k) tEB[k] = __expf(trans[j * KK + i0 + k]);
        float gl = pot[last * KK + j];
        float pr0 = pot[max(last - 1, 0) * KK + j];
        float pr1 = pot[max(last - 2, 0) * KK + j];
        float pr2 = pot[max(last - 3, 0) * KK + j];
        float pr3 = pot[max(last - 4, 0) * KK + j];
        float pr4 = pot[max(last - 5, 0) * KK + j];
        float pr5 = pot[max(last - 6, 0) * KK + j];
        float pr6 = pot[max(last - 7, 0) * KK + j];
        float pr7 = pot[max(last - 8, 0) * KK + j];
        int t = last - 1;
        for (; t - 7 >= m; t -= 8) {
            LSTEPB(t,     pr0); LSTEPB(t - 1, pr1);
            LSTEPB(t - 2, pr2); LSTEPB(t - 3, pr3);
            LSTEPB(t - 4, pr4); LSTEPB(t - 5, pr5);
            LSTEPB(t - 6, pr6); LSTEPB(t - 7, pr7);
        }
        if (t >= m) { LSTEPB(t, pr0); --t; }
        if (t >= m) { LSTEPB(t, pr1); --t; }
        if (t >= m) { LSTEPB(t, pr2); --t; }
        if (t >= m) { LSTEPB(t, pr3); --t; }
        if (t >= m) { LSTEPB(t, pr4); --t; }
        if (t >= m) { LSTEPB(t, pr5); --t; }
        if (t >= m) { LSTEPB(t, pr6); --t; }
        s_q[j] = gl;                    // gl_m
    }

    __syncthreads();

    if (role == 0 || role == 1) {
        // joint best at the meeting point (both waves compute it; avoids a sync)
        float v = s_a[j] + s_g[j] - pot[m * KK + j];
        float bv = v; int bj = j;
#pragma unroll
        for (int d = 1; d < 32; d <<= 1) {
            float ov = __shfl_xor(bv, d, 64);
            int   oj = __shfl_xor(bj, d, 64);
            if (ov > bv || (ov == bv && oj < bj)) { bv = ov; bj = oj; }
        }
        if (role == 0) {
            if (lane == 0) {
                out[(size_t)BB * TT + b] = bv;       // best_score
                out_tags[m] = (float)bj;             // meeting tag
            }
            // fwd backtrace: t in [0, m-1]; all chunks full (m % 32 == 0)
            const int C_f = m >> 5;
            int e = bj, my_e = bj;
            for (int c = C_f - 1; c >= 1; --c) {
                e = s_cmF[(c << 5) + e];             // tag @ 32*c (uniform)
                if (lane == c - 1) my_e = e;
            }
            if (lane < C_f) {
                int cur = my_e;                      // tag @ 32*(lane+1)
                const int tend = (lane << 5) + 32;
#pragma unroll
                for (int r = 0; r < 32; ++r) {
                    int tt = tend - r;
                    cur = s_bp[tt * KK + cur];       // tag @ tt-1
                    out_tags[tt - 1] = (float)cur;
                }
            }
        } else {
            // bwd backtrace: t in [m+1, last]; bp_bwd[t] stored at row t+1
            const int C_b = (last - m + 31) >> 5;
            int e = bj, my_e = bj;
            for (int c = 0; c < C_b; ++c) {
                if (lane == c) my_e = e;             // tag @ m+32c
                e = s_cmB[(c << 5) + e];
            }
            // e = tag @ last now
            if (lane < C_b) {
                int cur = my_e;
                const int tlo = m + (lane << 5);
                const int thi = min(tlo + 31, last - 1);
#pragma unroll
                for (int r = 0; r < 32; ++r) {
                    int tt = tlo + r;
                    if (tt <= thi) {
                        cur = s_bp[(tt + 1) * KK + cur];   // tag @ tt+1
                        out_tags[tt + 1] = (float)cur;
                    }
                }
            }
            for (int tt = last + 1 + lane; tt < TT; tt += 64)
                out_tags[tt] = (float)e;             // padding = final tag
        }
    } else if (role == 2) {
        // logZ = LSE_i(beta_m[i] + gl_m[i] - pot_m[i]); ll = su - logZ
        float v = s_p[j] + s_q[j] - pot[m * KK + j];
        float Mf = v;
#pragma unroll
        for (int d = 1; d < 32; d <<= 1) Mf = fmaxf(Mf, __shfl_xor(Mf, d, 64));
        float e = __expf(v - Mf);
#pragma unroll
        for (int d = 1; d < 32; d <<= 1) e += __shfl_xor(e, d, 64);
        float ln = Mf + __logf(e);
        if (lane == 0) out[(size_t)BB * TT + BB + b] -= ln;  // su was stashed pre-sync
    }
}

extern "C" void kernel_launch(void* const* d_in, const int* in_sizes, int n_in,
                              void* d_out, int out_size, void* d_ws, size_t ws_size,
                              hipStream_t stream) {
    const float* potentials = (const float*)d_in[0];
    const float* transitions = (const float*)d_in[1];
    const int* sequence_lengths = (const int*)d_in[2];
    const int* tag_indices = (const int*)d_in[3];
    float* out = (float*)d_out;
    int* perm = (int*)d_ws;
    const int use_perm = (ws_size >= BB * sizeof(int)) ? 1 : 0;
    if (use_perm)
        build_perm<<<1, 512, 0, stream>>>(sequence_lengths, perm);
    crf_kernel<<<BB / 2, 512, 0, stream>>>(potentials, transitions, sequence_lengths,
                                           tag_indices, out, perm, use_perm);
}

// Round 12
// 288.363 us; speedup vs baseline: 1.1114x; 1.0712x over previous
//
#include <hip/hip_runtime.h>

#define BB 2048
#define TT 512
#define KK 32

// 4-source viterbi block: strict > keeps first occurrence (np.argmax semantics)
// Named scalars ONLY — local arrays with non-constant indices get demoted to
// scratch (prior-session regression: 8x slowdown).
#define VBLK(q, t0, t1, t2, t3, base, m, bi) do {                       \
    float s0_ = (q).x + (t0), s1_ = (q).y + (t1);                       \
    float s2_ = (q).z + (t2), s3_ = (q).w + (t3);                       \
    m = s0_; bi = (base);                                               \
    if (s1_ > m) { m = s1_; bi = (base) + 1; }                          \
    if (s2_ > m) { m = s2_; bi = (base) + 2; }                          \
    if (s3_ > m) { m = s3_; bi = (base) + 3; }                          \
} while (0)

// Viterbi core (shared by clamped / no-clamp variants). NL = prefetch load
// expression. R6 lesson: LDS-broadcast beats readlane. R9/R10/R11 lessons:
// role rotation / fusion / pairing all regress — keep R8 structure.
#define VSTEPF_CORE(T, PR, NL) do {                                     \
    float nl_ = (NL);                                                   \
    s_a[j] = alpha;                                                     \
    __builtin_amdgcn_wave_barrier();                                    \
    const float4 q0 = *(const float4*)(s_a + i0);                       \
    const float4 q1 = *(const float4*)(s_a + i0 + 4);                   \
    const float4 q2 = *(const float4*)(s_a + i0 + 8);                   \
    const float4 q3 = *(const float4*)(s_a + i0 + 12);                  \
    float m0, m1, m2, m3; int b0, b1, b2, b3;                           \
    VBLK(q0, tA[0],  tA[1],  tA[2],  tA[3],  i0 + 0,  m0, b0);          \
    VBLK(q1, tA[4],  tA[5],  tA[6],  tA[7],  i0 + 4,  m1, b1);          \
    VBLK(q2, tA[8],  tA[9],  tA[10], tA[11], i0 + 8,  m2, b2);          \
    VBLK(q3, tA[12], tA[13], tA[14], tA[15], i0 + 12, m3, b3);          \
    if (m1 > m0) { m0 = m1; b0 = b1; }                                  \
    if (m3 > m2) { m2 = m3; b2 = b3; }                                  \
    if (m2 > m0) { m0 = m2; b0 = b2; }                                  \
    float om = __shfl_xor(m0, 32, 64);                                  \
    int   ob = __shfl_xor(b0, 32, 64);                                  \
    bool won = half ? (m0 > om) : (m0 >= om);                           \
    float mm = fmaxf(m0, om);                                           \
    int bwin_ = won ? b0 : ob;                                          \
    if (won) s_bp[(T) * KK + j] = (unsigned char)b0;                    \
    cmap = __shfl(cmap, bwin_, 64);                                     \
    if (((T) & 31) == 0) {                                              \
        s_cmF[((((T) >> 5) - 1) << 5) + j] = (unsigned char)cmap;       \
        cmap = j;                                                       \
    }                                                                   \
    alpha = PR + mm;                                                    \
    PR = nl_;                                                           \
} while (0)

#define VSTEPF(T, PR)          VSTEPF_CORE(T, PR, pot[min((T) + 8, last) * KK + j])
#define VSTEPF_NC(T, PR, OFS)  VSTEPF_CORE(T, PR, pfp[OFS])

#define VSTEPB_CORE(T, PR, NL) do {                                     \
    float nl_ = (NL);                                                   \
    s_g[j] = gamma;                                                     \
    __builtin_amdgcn_wave_barrier();                                    \
    const float4 q0 = *(const float4*)(s_g + i0);                       \
    const float4 q1 = *(const float4*)(s_g + i0 + 4);                   \
    const float4 q2 = *(const float4*)(s_g + i0 + 8);                   \
    const float4 q3 = *(const float4*)(s_g + i0 + 12);                  \
    float m0, m1, m2, m3; int b0, b1, b2, b3;                           \
    VBLK(q0, tB[0],  tB[1],  tB[2],  tB[3],  i0 + 0,  m0, b0);          \
    VBLK(q1, tB[4],  tB[5],  tB[6],  tB[7],  i0 + 4,  m1, b1);          \
    VBLK(q2, tB[8],  tB[9],  tB[10], tB[11], i0 + 8,  m2, b2);          \
    VBLK(q3, tB[12], tB[13], tB[14], tB[15], i0 + 12, m3, b3);          \
    if (m1 > m0) { m0 = m1; b0 = b1; }                                  \
    if (m3 > m2) { m2 = m3; b2 = b3; }                                  \
    if (m2 > m0) { m0 = m2; b0 = b2; }                                  \
    float om = __shfl_xor(m0, 32, 64);                                  \
    int   ob = __shfl_xor(b0, 32, 64);                                  \
    bool won = half ? (m0 > om) : (m0 >= om);                           \
    float mm = fmaxf(m0, om);                                           \
    int bwin_ = won ? b0 : ob;                                          \
    if (won) s_bp[((T) + 1) * KK + j] = (unsigned char)b0;              \
    cmapb = __shfl(cmapb, bwin_, 64);                                   \
    if ((((T) - m) & 31) == 0) {                                        \
        s_cmB[((((T) - m) >> 5) << 5) + j] = (unsigned char)cmapb;      \
        cmapb = j;                                                      \
    }                                                                   \
    gamma = PR + mm;                                                    \
    PR = nl_;                                                           \
} while (0)

#define VSTEPB(T, PR)          VSTEPB_CORE(T, PR, pot[max((T) - 8, 0) * KK + j])
#define VSTEPB_NC(T, PR, OFS)  VSTEPB_CORE(T, PR, pfp[OFS])

#define LSTEPF_CORE(T, PR, NL) do {                                     \
    float nl_ = (NL);                                                   \
    float M = __builtin_amdgcn_readfirstlane(beta);                     \
    float p = __expf(beta - M);                                         \
    s_p[j] = p;                                                         \
    __builtin_amdgcn_wave_barrier();                                    \
    const float4 q0 = *(const float4*)(s_p + i0);                       \
    const float4 q1 = *(const float4*)(s_p + i0 + 4);                   \
    const float4 q2 = *(const float4*)(s_p + i0 + 8);                   \
    const float4 q3 = *(const float4*)(s_p + i0 + 12);                  \
    float a0 = fmaf(q0.x, tE[0],  q0.y * tE[1]);                        \
    a0 = fmaf(q0.z, tE[2],  a0); a0 = fmaf(q0.w, tE[3],  a0);           \
    float a1 = fmaf(q1.x, tE[4],  q1.y * tE[5]);                        \
    a1 = fmaf(q1.z, tE[6],  a1); a1 = fmaf(q1.w, tE[7],  a1);           \
    float a2 = fmaf(q2.x, tE[8],  q2.y * tE[9]);                        \
    a2 = fmaf(q2.z, tE[10], a2); a2 = fmaf(q2.w, tE[11], a2);           \
    float a3 = fmaf(q3.x, tE[12], q3.y * tE[13]);                       \
    a3 = fmaf(q3.z, tE[14], a3); a3 = fmaf(q3.w, tE[15], a3);           \
    float ssum = (a0 + a1) + (a2 + a3);                                 \
    ssum += __shfl_xor(ssum, 32, 64);                                   \
    beta = PR + M + __logf(ssum);                                       \
    PR = nl_;                                                           \
} while (0)

#define LSTEPF(T, PR)          LSTEPF_CORE(T, PR, pot[min((T) + 8, last) * KK + j])
#define LSTEPF_NC(T, PR, OFS)  LSTEPF_CORE(T, PR, pfp[OFS])

#define LSTEPB_CORE(T, PR, NL) do {                                     \
    float nl_ = (NL);                                                   \
    float M = __builtin_amdgcn_readfirstlane(gl);                       \
    float p = __expf(gl - M);                                           \
    s_q[j] = p;                                                         \
    __builtin_amdgcn_wave_barrier();                                    \
    const float4 q0 = *(const float4*)(s_q + i0);                       \
    const float4 q1 = *(const float4*)(s_q + i0 + 4);                   \
    const float4 q2 = *(const float4*)(s_q + i0 + 8);                   \
    const float4 q3 = *(const float4*)(s_q + i0 + 12);                  \
    float a0 = fmaf(q0.x, tEB[0],  q0.y * tEB[1]);                      \
    a0 = fmaf(q0.z, tEB[2],  a0); a0 = fmaf(q0.w, tEB[3],  a0);         \
    float a1 = fmaf(q1.x, tEB[4],  q1.y * tEB[5]);                      \
    a1 = fmaf(q1.z, tEB[6],  a1); a1 = fmaf(q1.w, tEB[7],  a1);         \
    float a2 = fmaf(q2.x, tEB[8],  q2.y * tEB[9]);                      \
    a2 = fmaf(q2.z, tEB[10], a2); a2 = fmaf(q2.w, tEB[11], a2);         \
    float a3 = fmaf(q3.x, tEB[12], q3.y * tEB[13]);                     \
    a3 = fmaf(q3.z, tEB[14], a3); a3 = fmaf(q3.w, tEB[15], a3);         \
    float ssum = (a0 + a1) + (a2 + a3);                                 \
    ssum += __shfl_xor(ssum, 32, 64);                                   \
    gl = PR + M + __logf(ssum);                                         \
    PR = nl_;                                                           \
} while (0)

#define LSTEPB(T, PR)          LSTEPB_CORE(T, PR, pot[max((T) - 8, 0) * KK + j])
#define LSTEPB_NC(T, PR, OFS)  LSTEPB_CORE(T, PR, pfp[OFS])

// ---------- LPT scheduler: perm = block ids sorted by DESCENDING seqlen ----------
// Counting sort, 1 block / 512 threads. Verified R8 win (+48us): long blocks
// start first, shorts backfill -> makespan tail shrinks.
__launch_bounds__(512)
__global__ void build_perm(const int* __restrict__ seqlen,
                           int* __restrict__ perm) {
    __shared__ int hist[TT + 1];
    const int tid = threadIdx.x;
    for (int i = tid; i <= TT; i += 512) hist[i] = 0;
    __syncthreads();
    for (int i = tid; i < BB; i += 512) atomicAdd(&hist[seqlen[i]], 1);
    __syncthreads();
    if (tid == 0) {
        int acc = 0;
        for (int L = TT; L >= 1; --L) { int c = hist[L]; hist[L] = acc; acc += c; }
    }
    __syncthreads();
    for (int i = tid; i < BB; i += 512) {
        int pos = atomicAdd(&hist[seqlen[i]], 1);
        perm[pos] = i;
    }
}

__launch_bounds__(256)
__global__ void crf_kernel(const float* __restrict__ pot_g,
                           const float* __restrict__ trans,
                           const int* __restrict__ seqlen,
                           const int* __restrict__ tagidx,
                           float* __restrict__ out,
                           const int* __restrict__ perm,
                           int use_perm) {
    __shared__ __align__(16) float s_a[KK];          // fwd alpha broadcast (wv0)
    __shared__ __align__(16) float s_g[KK];          // bwd gamma broadcast (wv1)
    __shared__ __align__(16) float s_p[KK];          // fwd LSE broadcast (wv2)
    __shared__ __align__(16) float s_q[KK];          // bwd LSE broadcast (wv3)
    __shared__ unsigned char s_bp[TT * KK];          // fwd rows 1..m, bwd rows m+1..last
    __shared__ unsigned char s_cmF[8 * KK];          // fwd chunk maps (<=8 full chunks)
    __shared__ unsigned char s_cmB[10 * KK];         // bwd chunk maps (<=9 chunks)

    const int tid  = threadIdx.x;
    const int wv   = tid >> 6;
    const int lane = tid & 63;
    const int j    = lane & 31;
    const int half = lane >> 5;
    const int i0   = half << 4;
    const int b    = use_perm ? perm[blockIdx.x] : blockIdx.x;

    const float* pot = pot_g + (size_t)b * (TT * KK);
    const int len  = seqlen[b];
    const int last = len - 1;
    // meeting point: multiple of 32 so all fwd chunks are full
    const int m = ((last + 1) >> 1) & ~31;
    float* out_tags = out + (size_t)b * TT;

    // For last >= 64 (=> m >= 32): fwd prefetch rows 9..m+8 <= last and bwd
    // prefetch rows last-9..m-8 >= 0 are in-bounds WITHOUT clamping -> hot
    // loops use a striding base pointer + compile-time immediate offsets
    // (saves the per-step min/mul/64b-add address chain). Short sequences
    // keep the clamped loops.
    const bool fast = (last >= 64);

    if (wv == 0) {
        // ============ forward viterbi: alpha_0 .. alpha_m ============
        float tA[16];
#pragma unroll
        for (int k = 0; k < 16; ++k) tA[k] = trans[(i0 + k) * KK + j];
        int cmap = j;
        float alpha = pot[j];
        float pr0 = pot[min(1, last) * KK + j];
        float pr1 = pot[min(2, last) * KK + j];
        float pr2 = pot[min(3, last) * KK + j];
        float pr3 = pot[min(4, last) * KK + j];
        float pr4 = pot[min(5, last) * KK + j];
        float pr5 = pot[min(6, last) * KK + j];
        float pr6 = pot[min(7, last) * KK + j];
        float pr7 = pot[min(8, last) * KK + j];
        int t = 1;
        if (fast) {
            const float* pfp = pot + 9 * KK + j;     // row t+8 for t=1
            for (; t + 7 <= m; t += 8) {
                VSTEPF_NC(t,     pr0, 0 * KK); VSTEPF_NC(t + 1, pr1, 1 * KK);
                VSTEPF_NC(t + 2, pr2, 2 * KK); VSTEPF_NC(t + 3, pr3, 3 * KK);
                VSTEPF_NC(t + 4, pr4, 4 * KK); VSTEPF_NC(t + 5, pr5, 5 * KK);
                VSTEPF_NC(t + 6, pr6, 6 * KK); VSTEPF_NC(t + 7, pr7, 7 * KK);
                pfp += 8 * KK;
            }
        } else {
            for (; t + 7 <= m; t += 8) {
                VSTEPF(t,     pr0); VSTEPF(t + 1, pr1);
                VSTEPF(t + 2, pr2); VSTEPF(t + 3, pr3);
                VSTEPF(t + 4, pr4); VSTEPF(t + 5, pr5);
                VSTEPF(t + 6, pr6); VSTEPF(t + 7, pr7);
            }
        }
        // m % 32 == 0 with unroll 8: loop lands exactly on t = m+1.
        s_a[j] = alpha;                 // alpha_m
    } else if (wv == 1) {
        // ============ backward viterbi: gamma_last .. gamma_m ============
        float tB[16];
#pragma unroll
        for (int k = 0; k < 16; ++k) tB[k] = trans[j * KK + i0 + k];
        int cmapb = j;
        float gamma = pot[last * KK + j];
        float pr0 = pot[max(last - 1, 0) * KK + j];
        float pr1 = pot[max(last - 2, 0) * KK + j];
        float pr2 = pot[max(last - 3, 0) * KK + j];
        float pr3 = pot[max(last - 4, 0) * KK + j];
        float pr4 = pot[max(last - 5, 0) * KK + j];
        float pr5 = pot[max(last - 6, 0) * KK + j];
        float pr6 = pot[max(last - 7, 0) * KK + j];
        float pr7 = pot[max(last - 8, 0) * KK + j];
        int t = last - 1;
        if (fast) {
            const float* pfp = pot + (size_t)(last - 9) * KK + j;  // row t-8
            for (; t - 7 >= m; t -= 8) {
                VSTEPB_NC(t,     pr0, -(0 * KK)); VSTEPB_NC(t - 1, pr1, -(1 * KK));
                VSTEPB_NC(t - 2, pr2, -(2 * KK)); VSTEPB_NC(t - 3, pr3, -(3 * KK));
                VSTEPB_NC(t - 4, pr4, -(4 * KK)); VSTEPB_NC(t - 5, pr5, -(5 * KK));
                VSTEPB_NC(t - 6, pr6, -(6 * KK)); VSTEPB_NC(t - 7, pr7, -(7 * KK));
                pfp -= 8 * KK;
            }
        } else {
            for (; t - 7 >= m; t -= 8) {
                VSTEPB(t,     pr0); VSTEPB(t - 1, pr1);
                VSTEPB(t - 2, pr2); VSTEPB(t - 3, pr3);
                VSTEPB(t - 4, pr4); VSTEPB(t - 5, pr5);
                VSTEPB(t - 6, pr6); VSTEPB(t - 7, pr7);
            }
        }
        if (t >= m) { VSTEPB(t, pr0); --t; }
        if (t >= m) { VSTEPB(t, pr1); --t; }
        if (t >= m) { VSTEPB(t, pr2); --t; }
        if (t >= m) { VSTEPB(t, pr3); --t; }
        if (t >= m) { VSTEPB(t, pr4); --t; }
        if (t >= m) { VSTEPB(t, pr5); --t; }
        if (t >= m) { VSTEPB(t, pr6); --t; }
        s_g[j] = gamma;                 // gamma_m
    } else if (wv == 2) {
        // ============ seq-score + forward LSE: beta_0 .. beta_m ============
        float tE[16];
#pragma unroll
        for (int k = 0; k < 16; ++k) tE[k] = __expf(trans[(i0 + k) * KK + j]);
        const int* tagrow = tagidx + (size_t)b * TT;
        float su = 0.0f;
#pragma unroll
        for (int c = 0; c < TT / 64; ++c) {
            int tt = c * 64 + lane;
            if (tt < len) {
                int tg = tagrow[tt];
                su += pot[tt * KK + tg];
                if (tt < last) {
                    int tg2 = tagrow[tt + 1];
                    su += trans[tg * KK + tg2];
                }
            }
        }
#pragma unroll
        for (int d = 1; d < 64; d <<= 1) su += __shfl_xor(su, d, 64);
        if (lane == 0) out[(size_t)BB * TT + BB + b] = su;  // stash su; ln added post-sync

        float beta = pot[j];
        float pr0 = pot[min(1, last) * KK + j];
        float pr1 = pot[min(2, last) * KK + j];
        float pr2 = pot[min(3, last) * KK + j];
        float pr3 = pot[min(4, last) * KK + j];
        float pr4 = pot[min(5, last) * KK + j];
        float pr5 = pot[min(6, last) * KK + j];
        float pr6 = pot[min(7, last) * KK + j];
        float pr7 = pot[min(8, last) * KK + j];
        int t = 1;
        if (fast) {
            const float* pfp = pot + 9 * KK + j;
            for (; t + 7 <= m; t += 8) {
                LSTEPF_NC(t,     pr0, 0 * KK); LSTEPF_NC(t + 1, pr1, 1 * KK);
                LSTEPF_NC(t + 2, pr2, 2 * KK); LSTEPF_NC(t + 3, pr3, 3 * KK);
                LSTEPF_NC(t + 4, pr4, 4 * KK); LSTEPF_NC(t + 5, pr5, 5 * KK);
                LSTEPF_NC(t + 6, pr6, 6 * KK); LSTEPF_NC(t + 7, pr7, 7 * KK);
                pfp += 8 * KK;
            }
        } else {
            for (; t + 7 <= m; t += 8) {
                LSTEPF(t,     pr0); LSTEPF(t + 1, pr1);
                LSTEPF(t + 2, pr2); LSTEPF(t + 3, pr3);
                LSTEPF(t + 4, pr4); LSTEPF(t + 5, pr5);
                LSTEPF(t + 6, pr6); LSTEPF(t + 7, pr7);
            }
        }
        s_p[j] = beta;                  // beta_m
    } else {
        // ============ backward LSE: gl_last .. gl_m ============
        float tEB[16];
#pragma unroll
        for (int k = 0; k < 16; ++k) tEB[k] = __expf(trans[j * KK + i0 + k]);
        float gl = pot[last * KK + j];
        float pr0 = pot[max(last - 1, 0) * KK + j];
        float pr1 = pot[max(last - 2, 0) * KK + j];
        float pr2 = pot[max(last - 3, 0) * KK + j];
        float pr3 = pot[max(last - 4, 0) * KK + j];
        float pr4 = pot[max(last - 5, 0) * KK + j];
        float pr5 = pot[max(last - 6, 0) * KK + j];
        float pr6 = pot[max(last - 7, 0) * KK + j];
        float pr7 = pot[max(last - 8, 0) * KK + j];
        int t = last - 1;
        if (fast) {
            const float* pfp = pot + (size_t)(last - 9) * KK + j;
            for (; t - 7 >= m; t -= 8) {
                LSTEPB_NC(t,     pr0, -(0 * KK)); LSTEPB_NC(t - 1, pr1, -(1 * KK));
                LSTEPB_NC(t - 2, pr2, -(2 * KK)); LSTEPB_NC(t - 3, pr3, -(3 * KK));
                LSTEPB_NC(t - 4, pr4, -(4 * KK)); LSTEPB_NC(t - 5, pr5, -(5 * KK));
                LSTEPB_NC(t - 6, pr6, -(6 * KK)); LSTEPB_NC(t - 7, pr7, -(7 * KK));
                pfp -= 8 * KK;
            }
        } else {
            for (; t - 7 >= m; t -= 8) {
                LSTEPB(t,     pr0); LSTEPB(t - 1, pr1);
                LSTEPB(t - 2, pr2); LSTEPB(t - 3, pr3);
                LSTEPB(t - 4, pr4); LSTEPB(t - 5, pr5);
                LSTEPB(t - 6, pr6); LSTEPB(t - 7, pr7);
            }
        }
        if (t >= m) { LSTEPB(t, pr0); --t; }
        if (t >= m) { LSTEPB(t, pr1); --t; }
        if (t >= m) { LSTEPB(t, pr2); --t; }
        if (t >= m) { LSTEPB(t, pr3); --t; }
        if (t >= m) { LSTEPB(t, pr4); --t; }
        if (t >= m) { LSTEPB(t, pr5); --t; }
        if (t >= m) { LSTEPB(t, pr6); --t; }
        s_q[j] = gl;                    // gl_m
    }

    __syncthreads();

    if (wv == 0 || wv == 1) {
        // joint best at the meeting point (both waves compute it; avoids a sync)
        float v = s_a[j] + s_g[j] - pot[m * KK + j];
        float bv = v; int bj = j;
#pragma unroll
        for (int d = 1; d < 32; d <<= 1) {
            float ov = __shfl_xor(bv, d, 64);
            int   oj = __shfl_xor(bj, d, 64);
            if (ov > bv || (ov == bv && oj < bj)) { bv = ov; bj = oj; }
        }
        if (wv == 0) {
            if (lane == 0) {
                out[(size_t)BB * TT + b] = bv;       // best_score
                out_tags[m] = (float)bj;             // meeting tag
            }
            // fwd backtrace: t in [0, m-1]; all chunks full (m % 32 == 0)
            const int C_f = m >> 5;
            int e = bj, my_e = bj;
            for (int c = C_f - 1; c >= 1; --c) {
                e = s_cmF[(c << 5) + e];             // tag @ 32*c (uniform)
                if (lane == c - 1) my_e = e;
            }
            if (lane < C_f) {
                int cur = my_e;                      // tag @ 32*(lane+1)
                const int tend = (lane << 5) + 32;
#pragma unroll
                for (int r = 0; r < 32; ++r) {
                    int tt = tend - r;
                    cur = s_bp[tt * KK + cur];       // tag @ tt-1
                    out_tags[tt - 1] = (float)cur;
                }
            }
        } else {
            // bwd backtrace: t in [m+1, last]; bp_bwd[t] stored at row t+1
            const int C_b = (last - m + 31) >> 5;
            int e = bj, my_e = bj;
            for (int c = 0; c < C_b; ++c) {
                if (lane == c) my_e = e;             // tag @ m+32c
                e = s_cmB[(c << 5) + e];
            }
            // e = tag @ last now
            if (lane < C_b) {
                int cur = my_e;
                const int tlo = m + (lane << 5);
                const int thi = min(tlo + 31, last - 1);
#pragma unroll
                for (int r = 0; r < 32; ++r) {
                    int tt = tlo + r;
                    if (tt <= thi) {
                        cur = s_bp[(tt + 1) * KK + cur];   // tag @ tt+1
                        out_tags[tt + 1] = (float)cur;
                    }
                }
            }
            for (int tt = last + 1 + lane; tt < TT; tt += 64)
                out_tags[tt] = (float)e;             // padding = final tag
        }
    } else if (wv == 2) {
        // logZ = LSE_i(beta_m[i] + gl_m[i] - pot_m[i]); ll = su - logZ
        float v = s_p[j] + s_q[j] - pot[m * KK + j];
        float Mf = v;
#pragma unroll
        for (int d = 1; d < 32; d <<= 1) Mf = fmaxf(Mf, __shfl_xor(Mf, d, 64));
        float e = __expf(v - Mf);
#pragma unroll
        for (int d = 1; d < 32; d <<= 1) e += __shfl_xor(e, d, 64);
        float ln = Mf + __logf(e);
        if (lane == 0) out[(size_t)BB * TT + BB + b] -= ln;  // su was stashed pre-sync
    }
}

extern "C" void kernel_launch(void* const* d_in, const int* in_sizes, int n_in,
                              void* d_out, int out_size, void* d_ws, size_t ws_size,
                              hipStream_t stream) {
    const float* potentials = (const float*)d_in[0];
    const float* transitions = (const float*)d_in[1];
    const int* sequence_lengths = (const int*)d_in[2];
    const int* tag_indices = (const int*)d_in[3];
    float* out = (float*)d_out;
    int* perm = (int*)d_ws;
    const int use_perm = (ws_size >= BB * sizeof(int)) ? 1 : 0;
    if (use_perm)
        build_perm<<<1, 512, 0, stream>>>(sequence_lengths, perm);
    crf_kernel<<<BB, 256, 0, stream>>>(potentials, transitions, sequence_lengths,
                                       tag_indices, out, perm, use_perm);
}